// Round 1
// baseline (53.445 us; speedup 1.0000x reference)
//
#include <hip/hip_runtime.h>
#include <math.h>

// Problem constants (fixed instance):
//   size=1024, fcs=[1024,4096,4096,4874], N=4097, Nsample=256, Wc=4, NPTS=101
#define SIZE    1024
#define H1DIM   4096
#define H2DIM   4096
#define FCOUT   4874
#define NQ      4097      // N
#define NPTS    101
#define OUTLAST 524288    // 256*2*1024, index of the "last" scalar

// ---------------------------------------------------------------------------
// GEMV: y[r] = (relu?)( dot(W[r,:], x) + b[r] ), W row-major M x K.
// One 64-lane wave per row; float4 loads (16 B/lane) fully coalesced.
// ---------------------------------------------------------------------------
__global__ __launch_bounds__(256) void gemv_kernel(
    const float* __restrict__ W, const float* __restrict__ x,
    const float* __restrict__ b, float* __restrict__ y,
    int M, int K, int do_relu) {
    const int lane = threadIdx.x & 63;
    const int wid  = threadIdx.x >> 6;          // 0..3
    const int row  = blockIdx.x * 4 + wid;
    if (row >= M) return;                       // wave-uniform exit
    const float4* __restrict__ Wr = reinterpret_cast<const float4*>(W + (size_t)row * K);
    const float4* __restrict__ xv = reinterpret_cast<const float4*>(x);
    const int nv = K >> 2;                      // float4 count (K % 4 == 0)
    float acc = 0.f;
    for (int i = lane; i < nv; i += 64) {
        float4 w4 = Wr[i];
        float4 x4 = xv[i];
        acc += w4.x * x4.x + w4.y * x4.y + w4.z * x4.z + w4.w * x4.w;
    }
    #pragma unroll
    for (int off = 32; off > 0; off >>= 1)
        acc += __shfl_down(acc, off);
    if (lane == 0) {
        float v = acc + b[row];
        if (do_relu) v = fmaxf(v, 0.f);
        y[row] = v;
    }
}

// ---------------------------------------------------------------------------
// Sigma[i] = mean(out_fc[i .. i+9]), i in [0, 4097); also per-block partial
// sums of min(Sigma, 0) for the "last" scalar.
// ---------------------------------------------------------------------------
__global__ __launch_bounds__(256) void sigma_kernel(
    const float* __restrict__ fc, float* __restrict__ Sigma,
    float* __restrict__ partials) {
    const int i = blockIdx.x * 256 + threadIdx.x;
    float m = 0.f;
    if (i < NQ) {
        float s = 0.f;
        #pragma unroll
        for (int k = 0; k < 10; ++k) s += fc[i + k];
        s *= 0.1f;
        Sigma[i] = s;
        m = fminf(s, 0.f);
    }
    __shared__ float red[4];
    const int lane = threadIdx.x & 63, w = threadIdx.x >> 6;
    #pragma unroll
    for (int off = 32; off > 0; off >>= 1) m += __shfl_down(m, off);
    if (lane == 0) red[w] = m;
    __syncthreads();
    if (threadIdx.x == 0)
        partials[blockIdx.x] = red[0] + red[1] + red[2] + red[3];
}

// ---------------------------------------------------------------------------
// Main interp/trapz stage. One thread per (i,j) in 256 x 1024.
//   chem  = atan(c0[i] + c2[i]*x[j]^2) * (8/pi)
//   q_k   = 4*x[j]*t_k + chem,  t_k = -1 + 0.02k
//   S     = lerp of Sigma at q_k on uniform grid [-8, 8], 4097 pts (clamped)
//   I1    = sum_k a_k * S ;  I2 = x[j] * sum_k b_k * S
//   out[i*2048 + j] = I1 ; out[i*2048 + 1024 + j] = -I2
// a_k = 0.08 * c_k * g(t_k), b_k = 4*t_k*a_k, g(t)=e^{4t}/(e^{4t}+1)^2,
// c_k = 0.5 at ends (trapz). The 1/x[j] in w cancels the x[j] in dx.
// ---------------------------------------------------------------------------
__global__ __launch_bounds__(256) void interp_kernel(
    const float* __restrict__ fc, const float* __restrict__ x,
    const float* __restrict__ Sigma, const float* __restrict__ partials,
    float* __restrict__ out) {
    __shared__ float sS[NQ];
    __shared__ float sA[NPTS], sB[NPTS];
    for (int i = threadIdx.x; i < NQ; i += 256) sS[i] = Sigma[i];
    if (threadIdx.x < NPTS) {
        const int k = threadIdx.x;
        float t  = fmaf(0.02f, (float)k, -1.f);
        float eu = __expf(4.f * t);
        float g  = eu / ((eu + 1.f) * (eu + 1.f));
        float c  = (k == 0 || k == NPTS - 1) ? 0.5f : 1.f;
        float a  = 0.08f * c * g;
        sA[k] = a;
        sB[k] = 4.f * t * a;
    }
    __syncthreads();

    const int gid = blockIdx.x * 256 + threadIdx.x;   // 0 .. 262143
    const int i = gid >> 10;                          // sample index, 0..255
    const int j = gid & 1023;                         // x index
    const float xj  = x[j];
    const float c0  = fc[NQ + 9 + 3 * i];
    const float c2  = fc[NQ + 9 + 3 * i + 2];
    const float chem = atanf(fmaf(c2, xj * xj, c0)) * 2.5464790894703254f; // 8/pi
    const float fourx = 4.f * xj;

    float acc1 = 0.f, acc2 = 0.f;
    #pragma unroll 4
    for (int k = 0; k < NPTS; ++k) {
        float t   = fmaf(0.02f, (float)k, -1.f);
        float q   = fmaf(fourx, t, chem);
        float pos = (q + 8.f) * 256.f;                 // grid spacing 1/256
        pos = fminf(fmaxf(pos, 0.f), 4096.f);
        int idx = (int)pos;
        if (idx > NQ - 2) idx = NQ - 2;
        float frac = pos - (float)idx;
        float s0 = sS[idx];
        float s  = fmaf(frac, sS[idx + 1] - s0, s0);
        acc1 = fmaf(sA[k], s, acc1);
        acc2 = fmaf(sB[k], s, acc2);
    }
    out[i * 2048 + j]        = acc1;
    out[i * 2048 + 1024 + j] = -xj * acc2;

    if (blockIdx.x == 0 && threadIdx.x == 0) {
        float last = 0.f;
        for (int p = 0; p < 17; ++p) last += partials[p];
        out[OUTLAST] = last;
    }
}

// ---------------------------------------------------------------------------
extern "C" void kernel_launch(void* const* d_in, const int* in_sizes, int n_in,
                              void* d_out, int out_size, void* d_ws, size_t ws_size,
                              hipStream_t stream) {
    const float* x  = (const float*)d_in[0];
    const float* W0 = (const float*)d_in[1];
    const float* b0 = (const float*)d_in[2];
    const float* W1 = (const float*)d_in[3];
    const float* b1 = (const float*)d_in[4];
    const float* W2 = (const float*)d_in[5];
    const float* b2 = (const float*)d_in[6];
    float* out = (float*)d_out;

    float* ws       = (float*)d_ws;
    float* h0       = ws;                 // 4096
    float* h1       = ws + 4096;          // 4096
    float* fc       = ws + 8192;          // 4874
    float* Sigma    = ws + 13312;         // 4097
    float* partials = ws + 17664;         // 17

    gemv_kernel<<<H1DIM / 4, 256, 0, stream>>>(W0, x,  b0, h0, H1DIM, SIZE,  1);
    gemv_kernel<<<H2DIM / 4, 256, 0, stream>>>(W1, h0, b1, h1, H2DIM, H1DIM, 1);
    gemv_kernel<<<(FCOUT + 3) / 4, 256, 0, stream>>>(W2, h1, b2, fc, FCOUT, H2DIM, 0);
    sigma_kernel<<<17, 256, 0, stream>>>(fc, Sigma, partials);
    interp_kernel<<<1024, 256, 0, stream>>>(fc, x, Sigma, partials, out);
}